// Round 6
// baseline (29459.964 us; speedup 1.0000x reference)
//
#include <hip/hip_runtime.h>
#include <math.h>

typedef __attribute__((ext_vector_type(8))) short short8;
typedef __attribute__((ext_vector_type(4))) float f32x4;

constexpr int NV = 50000;    // V
constexpr int NL = 100000;   // 2V literal rows
constexpr int NC = 200000;   // clauses
constexpr int NE = 300000;   // edges per polarity
constexpr int NROUNDS = 26;

__device__ __forceinline__ float sigf(float x) { return 1.0f / (1.0f + expf(-x)); }

// in-register f32 -> bf16 hi/lo split (truncation; combined rel err ~2^-16)
__device__ __forceinline__ void split8(const float* a, short8& h, short8& l) {
#pragma unroll
    for (int j = 0; j < 8; j++) {
        unsigned u = __float_as_uint(a[j]);
        h[j] = (short)(u >> 16);
        float lf = a[j] - __uint_as_float(u & 0xffff0000u);
        l[j] = (short)(__float_as_uint(lf) >> 16);
    }
}

// weight split with RTN on both halves (one-time prep)
__device__ __forceinline__ void splitw(float x, unsigned short* h, unsigned short* l) {
    unsigned u = __float_as_uint(x);
    unsigned hr = (u + 0x7fffu + ((u >> 16) & 1u)) & 0xffff0000u;
    float lf = x - __uint_as_float(hr);
    unsigned ul = __float_as_uint(lf);
    *h = (unsigned short)(hr >> 16);
    *l = (unsigned short)((ul + 0x7fffu + ((ul >> 16) & 1u)) >> 16);
}

// ======== weight prep: fragment-major packed layouts (coalesced 64-lane frag loads) ========
// frag id layout: (((kt*NT + tile)*64 + lane)*8 + j); element = W^T[n = tile*16 + (lane&15)][k = kt*32 + (lane>>4)*8 + j]

// MLP: W[3][k][n] -> packed frags, NT=8, 4 kts, 3 layers
__global__ __launch_bounds__(256) void pack_mlp_frag(
    const float* __restrict__ W, unsigned short* __restrict__ Wh, unsigned short* __restrict__ Wl)
{
    int fid = blockIdx.x * 256 + threadIdx.x;   // over 3*4*8*64 = 6144
    if (fid >= 6144) return;
    int lane = fid & 63;
    int tile = (fid >> 6) & 7;
    int kt = (fid >> 9) & 3;
    int layer = fid >> 11;
    int l15 = lane & 15, lg = lane >> 4;
    int n = tile * 16 + l15;
#pragma unroll
    for (int j = 0; j < 8; j++) {
        int k = kt * 32 + lg * 8 + j;
        unsigned short h, l;
        splitw(W[layer * 16384 + k * 128 + n], &h, &l);
        Wh[(size_t)fid * 8 + j] = h;
        Wl[(size_t)fid * 8 + j] = l;
    }
}

// LSTM: [Wih | Whh] -> packed frags, NT=32 (512 cols / 16), nstep kts
__global__ __launch_bounds__(256) void pack_lstm_frag(
    const float* __restrict__ Wih, const float* __restrict__ Whh, int kih, int nstep,
    unsigned short* __restrict__ Wh, unsigned short* __restrict__ Wl)
{
    int fid = blockIdx.x * 256 + threadIdx.x;   // over nstep*32*64
    if (fid >= nstep * 2048) return;
    int lane = fid & 63;
    int tile = (fid >> 6) & 31;
    int kt = fid >> 11;
    int l15 = lane & 15, lg = lane >> 4;
    int n = tile * 16 + l15;
#pragma unroll
    for (int j = 0; j < 8; j++) {
        int k = kt * 32 + lg * 8 + j;
        float v = (k < kih) ? Wih[n * kih + k] : Whh[(n << 7) + (k - kih)];
        unsigned short h, l;
        splitw(v, &h, &l);
        Wh[(size_t)fid * 8 + j] = h;
        Wl[(size_t)fid * 8 + j] = l;
    }
}

// ================= CSR build (once per call; graph is static across rounds) =================
__global__ __launch_bounds__(256) void csr_hist_k(
    const int* __restrict__ ps, const int* __restrict__ pd,
    const int* __restrict__ ns, const int* __restrict__ nd,
    int* __restrict__ cnt_c, int* __restrict__ cnt_l)
{
    int e = blockIdx.x * 256 + threadIdx.x;
    if (e >= NE) return;
    atomicAdd(&cnt_c[pd[e]], 1);
    atomicAdd(&cnt_c[nd[e]], 1);
    atomicAdd(&cnt_l[ps[e]], 1);
    atomicAdd(&cnt_l[NV + ns[e]], 1);
}

__global__ __launch_bounds__(256) void scan_p1(
    const int* __restrict__ cnt, int* __restrict__ partials, int n)
{
    __shared__ int sdata[256];
    int t = threadIdx.x, b = blockIdx.x;
    int base = b * 1024 + t * 4;
    int s = 0;
#pragma unroll
    for (int j = 0; j < 4; j++) { int i = base + j; if (i < n) s += cnt[i]; }
    sdata[t] = s; __syncthreads();
    for (int st = 128; st > 0; st >>= 1) {
        if (t < st) sdata[t] += sdata[t + st];
        __syncthreads();
    }
    if (t == 0) partials[b] = sdata[0];
}

__global__ __launch_bounds__(256) void scan_p2(int* __restrict__ partials, int nb, int* __restrict__ rowptr_end)
{
    __shared__ int sdata[256];
    int t = threadIdx.x;
    int v = (t < nb) ? partials[t] : 0;
    int x = v;
    sdata[t] = x; __syncthreads();
    for (int st = 1; st < 256; st <<= 1) {
        int y = (t >= st) ? sdata[t - st] : 0;
        __syncthreads();
        x += y; sdata[t] = x;
        __syncthreads();
    }
    if (t < nb) partials[t] = x - v;
    if (t == 255) *rowptr_end = sdata[255];
}

__global__ __launch_bounds__(256) void scan_p3(
    const int* __restrict__ cnt, const int* __restrict__ partials,
    int* __restrict__ rowptr, int* __restrict__ cursor, int n)
{
    __shared__ int sdata[256];
    int t = threadIdx.x, b = blockIdx.x;
    int base = b * 1024 + t * 4;
    int v[4]; int s = 0;
#pragma unroll
    for (int j = 0; j < 4; j++) { int i = base + j; v[j] = (i < n) ? cnt[i] : 0; s += v[j]; }
    int x = s;
    sdata[t] = x; __syncthreads();
    for (int st = 1; st < 256; st <<= 1) {
        int y = (t >= st) ? sdata[t - st] : 0;
        __syncthreads();
        x += y; sdata[t] = x;
        __syncthreads();
    }
    int off = partials[b] + x - s;
#pragma unroll
    for (int j = 0; j < 4; j++) {
        int i = base + j;
        if (i < n) { rowptr[i] = off; cursor[i] = off; off += v[j]; }
    }
}

__global__ __launch_bounds__(256) void csr_fill_k(
    const int* __restrict__ ps, const int* __restrict__ pd,
    const int* __restrict__ ns, const int* __restrict__ nd,
    int* __restrict__ cur_c, int* __restrict__ eidx_c,
    int* __restrict__ cur_l, int* __restrict__ eidx_l)
{
    int e = blockIdx.x * 256 + threadIdx.x;
    if (e >= NE) return;
    int p;
    p = atomicAdd(&cur_c[pd[e]], 1); eidx_c[p] = ps[e];
    p = atomicAdd(&cur_c[nd[e]], 1); eidx_c[p] = NV + ns[e];
    p = atomicAdd(&cur_l[ps[e]], 1); eidx_l[p] = pd[e];
    p = atomicAdd(&cur_l[NV + ns[e]], 1); eidx_l[p] = nd[e];
}

// ---- gather-sum: out[row] = sum_{j in segment} msg[eidx[j]] ; one wave per row ----
__global__ __launch_bounds__(256) void gather_sum_k(
    const float* __restrict__ msg, const int* __restrict__ rowptr,
    const int* __restrict__ eidx, float* __restrict__ out, int nrows)
{
    int row = (blockIdx.x * 256 + threadIdx.x) >> 6;
    if (row >= nrows) return;
    int lane = threadIdx.x & 63;
    int beg = rowptr[row], end = rowptr[row + 1];
    float ax = 0.f, ay = 0.f;
    for (int j = beg; j < end; j++) {
        int src = eidx[j];
        float2 v = *reinterpret_cast<const float2*>(msg + (size_t)src * 128 + lane * 2);
        ax += v.x; ay += v.y;
    }
    *reinterpret_cast<float2*>(out + (size_t)row * 128 + lane * 2) = make_float2(ax, ay);
}

// ---------------- fused 3-layer MLP: LDS only for activations, B frags direct from L2 ----------------
// block 256 (4 waves), BM=64; wave tile 32 rows x 64 cols
__global__ __launch_bounds__(256, 4) void mlp3_v2(
    const float* __restrict__ x, const unsigned short* __restrict__ Wh,
    const unsigned short* __restrict__ Wl, const float* __restrict__ bias,
    float* __restrict__ y, int M)
{
    __shared__ float Xs[64][132];
    const int t = threadIdx.x;
    const int rb = blockIdx.x * 64;
    const int lane = t & 63, w = t >> 6, wr = w >> 1, wc = w & 1;
    const int l15 = lane & 15, lg = lane >> 4;

#pragma unroll
    for (int j = 0; j < 8; j++) {
        int i = t + 256 * j;
        int r = i >> 5, c4 = i & 31;
        int gr = rb + r; if (gr >= M) gr = M - 1;
        *reinterpret_cast<float4*>(&Xs[r][c4 * 4]) =
            *reinterpret_cast<const float4*>(x + (size_t)gr * 128 + c4 * 4);
    }
    __syncthreads();

    for (int layer = 0; layer < 3; layer++) {
        f32x4 acc[2][4];
#pragma unroll
        for (int m = 0; m < 2; m++)
#pragma unroll
            for (int nf = 0; nf < 4; nf++) acc[m][nf] = f32x4{0.f, 0.f, 0.f, 0.f};

#pragma unroll
        for (int kt = 0; kt < 4; kt++) {
            short8 ah[2], al[2];
#pragma unroll
            for (int m = 0; m < 2; m++) {
                int row = wr * 32 + m * 16 + l15;
                float av[8];
                *reinterpret_cast<float4*>(&av[0]) =
                    *reinterpret_cast<const float4*>(&Xs[row][kt * 32 + lg * 8]);
                *reinterpret_cast<float4*>(&av[4]) =
                    *reinterpret_cast<const float4*>(&Xs[row][kt * 32 + lg * 8 + 4]);
                split8(av, ah[m], al[m]);
            }
#pragma unroll
            for (int nf = 0; nf < 4; nf++) {
                int tile = wc * 4 + nf;
                size_t off = ((size_t)(((layer * 4 + kt) * 8) + tile) * 64 + lane) * 8;
                short8 bh = *reinterpret_cast<const short8*>(Wh + off);
                short8 bl = *reinterpret_cast<const short8*>(Wl + off);
#pragma unroll
                for (int m = 0; m < 2; m++) {
                    acc[m][nf] = __builtin_amdgcn_mfma_f32_16x16x32_bf16(ah[m], bh, acc[m][nf], 0, 0, 0);
                    acc[m][nf] = __builtin_amdgcn_mfma_f32_16x16x32_bf16(ah[m], bl, acc[m][nf], 0, 0, 0);
                    acc[m][nf] = __builtin_amdgcn_mfma_f32_16x16x32_bf16(al[m], bh, acc[m][nf], 0, 0, 0);
                }
            }
        }
        float bv[4];
#pragma unroll
        for (int nf = 0; nf < 4; nf++) bv[nf] = bias[layer * 128 + wc * 64 + nf * 16 + l15];
        __syncthreads();   // all Xs reads done
        if (layer < 2) {
#pragma unroll
            for (int m = 0; m < 2; m++)
#pragma unroll
                for (int nf = 0; nf < 4; nf++)
#pragma unroll
                    for (int rr = 0; rr < 4; rr++) {
                        float v = fmaxf(acc[m][nf][rr] + bv[nf], 0.f);
                        Xs[wr * 32 + m * 16 + lg * 4 + rr][wc * 64 + nf * 16 + l15] = v;
                    }
            __syncthreads();
        } else {
#pragma unroll
            for (int m = 0; m < 2; m++)
#pragma unroll
                for (int rr = 0; rr < 4; rr++) {
                    int gr = rb + wr * 32 + m * 16 + lg * 4 + rr;
                    if (gr < M) {
#pragma unroll
                        for (int nf = 0; nf < 4; nf++)
                            y[(size_t)gr * 128 + wc * 64 + nf * 16 + l15] = acc[m][nf][rr] + bv[nf];
                    }
                }
        }
    }
}

// ---------------- LSTM v2: no LDS, no barriers; A + packed-B frags direct from cache ----------------
// block 256 (4 waves), BM=64; wave tile 32 rows x 256 gate-cols
template <int NSTEP, bool FLIP>
__global__ __launch_bounds__(256, 2) void lstm_v2(
    const float* __restrict__ A0, const float* __restrict__ A1, const float* __restrict__ A2,
    const unsigned short* __restrict__ Bh_g, const unsigned short* __restrict__ Bl_g,
    const float* __restrict__ bih, const float* __restrict__ bhh,
    float* __restrict__ c_st, float* __restrict__ h_out, int M)
{
    const int t = threadIdx.x;
    const int rb = blockIdx.x * 64;
    const int lane = t & 63, w = t >> 6, wr = w >> 1, wc = w & 1;
    const int l15 = lane & 15, lg = lane >> 4;

    f32x4 acc[2][16];
#pragma unroll
    for (int m = 0; m < 2; m++)
#pragma unroll
        for (int nr = 0; nr < 16; nr++) acc[m][nr] = f32x4{0.f, 0.f, 0.f, 0.f};

    int row[2];
#pragma unroll
    for (int m = 0; m < 2; m++) {
        int r = rb + wr * 32 + m * 16 + l15;
        row[m] = (r < M) ? r : (M - 1);
    }

#pragma unroll
    for (int seg = 0; seg < NSTEP / 4; seg++) {
        const float* src = (seg == 0) ? A0 : ((seg == 1) ? A1 : A2);
        int srow[2];
#pragma unroll
        for (int m = 0; m < 2; m++) {
            int r = row[m];
            if (FLIP && NSTEP == 12 && seg == 1) r = (r < NV) ? r + NV : r - NV;
            srow[m] = r;
        }
#pragma unroll
        for (int k2 = 0; k2 < 4; k2++) {
            const int kt = seg * 4 + k2;
            short8 ah[2], al[2];
#pragma unroll
            for (int m = 0; m < 2; m++) {
                const float* p = src + (size_t)srow[m] * 128 + k2 * 32 + lg * 8;
                float av[8];
                *reinterpret_cast<float4*>(&av[0]) = *reinterpret_cast<const float4*>(p);
                *reinterpret_cast<float4*>(&av[4]) = *reinterpret_cast<const float4*>(p + 4);
                split8(av, ah[m], al[m]);
            }
            const size_t fb = (size_t)kt * 32 * 64;   // frag-lane base for this kt
#pragma unroll
            for (int nr = 0; nr < 16; nr++) {
                int g = nr >> 2, nf = nr & 3;
                int tile = g * 8 + wc * 4 + nf;
                size_t off = (fb + (size_t)tile * 64 + lane) * 8;
                short8 bh = *reinterpret_cast<const short8*>(Bh_g + off);
                short8 bl = *reinterpret_cast<const short8*>(Bl_g + off);
#pragma unroll
                for (int m = 0; m < 2; m++) {
                    acc[m][nr] = __builtin_amdgcn_mfma_f32_16x16x32_bf16(ah[m], bh, acc[m][nr], 0, 0, 0);
                    acc[m][nr] = __builtin_amdgcn_mfma_f32_16x16x32_bf16(ah[m], bl, acc[m][nr], 0, 0, 0);
                    acc[m][nr] = __builtin_amdgcn_mfma_f32_16x16x32_bf16(al[m], bh, acc[m][nr], 0, 0, 0);
                }
            }
        }
    }

    // epilogue: bias + activations + state update
    float bs[4][4];
#pragma unroll
    for (int g = 0; g < 4; g++)
#pragma unroll
        for (int nf = 0; nf < 4; nf++) {
            int c = g * 128 + wc * 64 + nf * 16 + l15;
            bs[g][nf] = bih[c] + bhh[c];
        }
#pragma unroll
    for (int m = 0; m < 2; m++)
#pragma unroll
        for (int rr = 0; rr < 4; rr++) {
            int gr = rb + wr * 32 + m * 16 + lg * 4 + rr;
            if (gr >= M) continue;
#pragma unroll
            for (int nf = 0; nf < 4; nf++) {
                int colc = wc * 64 + nf * 16 + l15;
                float gi = acc[m][nf][rr]      + bs[0][nf];
                float gf = acc[m][4 + nf][rr]  + bs[1][nf];
                float gg = acc[m][8 + nf][rr]  + bs[2][nf];
                float go = acc[m][12 + nf][rr] + bs[3][nf];
                size_t p = (size_t)gr * 128 + colc;
                float cold = c_st[p];
                float cn = sigf(gf) * cold + sigf(gi) * tanhf(gg);
                float hn = sigf(go) * tanhf(cn);
                c_st[p] = cn;
                h_out[p] = hn;
            }
        }
}

extern "C" void kernel_launch(void* const* d_in, const int* in_sizes, int n_in,
                              void* d_out, int out_size, void* d_ws, size_t ws_size,
                              hipStream_t stream)
{
    const float* l_pos   = (const float*)d_in[0];
    const float* l_neg   = (const float*)d_in[1];
    const float* c_emb   = (const float*)d_in[2];
    const float* l_mlp_W = (const float*)d_in[3];
    const float* l_mlp_b = (const float*)d_in[4];
    const float* c_mlp_W = (const float*)d_in[5];
    const float* c_mlp_b = (const float*)d_in[6];
    const float* l_Wih   = (const float*)d_in[7];
    const float* l_Whh   = (const float*)d_in[8];
    const float* l_bih   = (const float*)d_in[9];
    const float* l_bhh   = (const float*)d_in[10];
    const float* c_Wih   = (const float*)d_in[11];
    const float* c_Whh   = (const float*)d_in[12];
    const float* c_bih   = (const float*)d_in[13];
    const float* c_bhh   = (const float*)d_in[14];
    const int* pos_src   = (const int*)d_in[15];
    const int* pos_dst   = (const int*)d_in[16];
    const int* neg_src   = (const int*)d_in[17];
    const int* neg_dst   = (const int*)d_in[18];

    float* out  = (float*)d_out;
    float* l_hA = out;
    float* c_h  = out + (size_t)NL * 128;

    float* wsp = (float*)d_ws;
    float* l_hB  = wsp; wsp += (size_t)NL * 128;
    float* l_c   = wsp; wsp += (size_t)NL * 128;
    float* c_c   = wsp; wsp += (size_t)NC * 128;
    float* l_msg = wsp; wsp += (size_t)NL * 128;
    float* c_msg = wsp; wsp += (size_t)NC * 128;
    float* l2c   = wsp; wsp += (size_t)NC * 128;
    float* c2l = l_msg;  // reused after l_msg consumed (gather #1 reads l_msg before gather #2 writes)

    unsigned short* us = (unsigned short*)wsp;
    unsigned short* mlpLh = us; us += 3 * 128 * 128;
    unsigned short* mlpLl = us; us += 3 * 128 * 128;
    unsigned short* mlpCh = us; us += 3 * 128 * 128;
    unsigned short* mlpCl = us; us += 3 * 128 * 128;
    unsigned short* lstmLh = us; us += 512 * 384;
    unsigned short* lstmLl = us; us += 512 * 384;
    unsigned short* lstmCh = us; us += 512 * 256;
    unsigned short* lstmCl = us; us += 512 * 256;

    int* ip = (int*)us;
    int* cnt_c    = ip; ip += NC;
    int* rowptr_c = ip; ip += NC + 1;
    int* cur_c    = ip; ip += NC;
    int* eidx_c   = ip; ip += 2 * NE;
    int* cnt_l    = ip; ip += NL;
    int* rowptr_l = ip; ip += NL + 1;
    int* cur_l    = ip; ip += NL;
    int* eidx_l   = ip; ip += 2 * NE;
    int* part_c   = ip; ip += 256;
    int* part_l   = ip; ip += 256;

    // init states
    hipMemcpyAsync(l_hA, l_pos, (size_t)NV * 128 * 4, hipMemcpyDeviceToDevice, stream);
    hipMemcpyAsync(l_hA + (size_t)NV * 128, l_neg, (size_t)NV * 128 * 4, hipMemcpyDeviceToDevice, stream);
    hipMemcpyAsync(c_h, c_emb, (size_t)NC * 128 * 4, hipMemcpyDeviceToDevice, stream);
    hipMemsetAsync(l_c, 0, (size_t)NL * 128 * 4, stream);
    hipMemsetAsync(c_c, 0, (size_t)NC * 128 * 4, stream);

    // pack weights into fragment-major layouts (once per call)
    pack_mlp_frag<<<24, 256, 0, stream>>>(l_mlp_W, mlpLh, mlpLl);
    pack_mlp_frag<<<24, 256, 0, stream>>>(c_mlp_W, mlpCh, mlpCl);
    pack_lstm_frag<<<96, 256, 0, stream>>>(l_Wih, l_Whh, 256, 12, lstmLh, lstmLl);
    pack_lstm_frag<<<64, 256, 0, stream>>>(c_Wih, c_Whh, 128, 8, lstmCh, lstmCl);

    // ---- CSR build (once per call; graph static across rounds) ----
    hipMemsetAsync(cnt_c, 0, NC * sizeof(int), stream);
    hipMemsetAsync(cnt_l, 0, NL * sizeof(int), stream);
    constexpr int EB = (NE + 255) / 256;
    csr_hist_k<<<EB, 256, 0, stream>>>(pos_src, pos_dst, neg_src, neg_dst, cnt_c, cnt_l);
    constexpr int NBC = (NC + 1023) / 1024;
    constexpr int NBL = (NL + 1023) / 1024;
    scan_p1<<<NBC, 256, 0, stream>>>(cnt_c, part_c, NC);
    scan_p2<<<1, 256, 0, stream>>>(part_c, NBC, rowptr_c + NC);
    scan_p3<<<NBC, 256, 0, stream>>>(cnt_c, part_c, rowptr_c, cur_c, NC);
    scan_p1<<<NBL, 256, 0, stream>>>(cnt_l, part_l, NL);
    scan_p2<<<1, 256, 0, stream>>>(part_l, NBL, rowptr_l + NL);
    scan_p3<<<NBL, 256, 0, stream>>>(cnt_l, part_l, rowptr_l, cur_l, NL);
    csr_fill_k<<<EB, 256, 0, stream>>>(pos_src, pos_dst, neg_src, neg_dst,
                                       cur_c, eidx_c, cur_l, eidx_l);

    float* l_cur = l_hA;
    float* l_nxt = l_hB;

    for (int r = 0; r < NROUNDS; r++) {
        mlp3_v2<<<(NL + 63) / 64, 256, 0, stream>>>(l_cur, mlpLh, mlpLl, l_mlp_b, l_msg, NL);
        mlp3_v2<<<(NC + 63) / 64, 256, 0, stream>>>(c_h, mlpCh, mlpCl, c_mlp_b, c_msg, NC);

        gather_sum_k<<<NC * 64 / 256, 256, 0, stream>>>(l_msg, rowptr_c, eidx_c, l2c, NC);
        gather_sum_k<<<NL * 64 / 256, 256, 0, stream>>>(c_msg, rowptr_l, eidx_l, c2l, NL);

        lstm_v2<12, true><<<(NL + 63) / 64, 256, 0, stream>>>(
            c2l, l_cur, l_cur, lstmLh, lstmLl, l_bih, l_bhh, l_c, l_nxt, NL);
        lstm_v2<8, false><<<(NC + 63) / 64, 256, 0, stream>>>(
            l2c, c_h, nullptr, lstmCh, lstmCl, c_bih, c_bhh, c_c, c_h, NC);

        float* t2 = l_cur; l_cur = l_nxt; l_nxt = t2;
    }
    (void)in_sizes; (void)n_in; (void)out_size; (void)ws_size;
}